// Round 2
// baseline (1361.440 us; speedup 1.0000x reference)
//
#include <hip/hip_runtime.h>

// Problem constants
#define BB     512
#define CC     22
#define TT     1000
#define HH     64
#define NCLS   4
#define MB     16          // batch rows per block
#define NBLK   (BB / MB)   // 32 blocks
#define TC     50          // time chunk staged in LDS
#define NCHUNK (TT / TC)
#define HS     34          // dwords per hbuf row (64 bf16 = 32 dwords, +2 pad)

typedef __attribute__((ext_vector_type(8))) short s16x8;  // 8 bf16 (4 VGPRs)
typedef __attribute__((ext_vector_type(4))) float f32x4;  // MFMA acc

union U4 { uint4 u; s16x8 v; };

__device__ __forceinline__ unsigned short f2bf(float f) {  // RNE
    unsigned int u = __float_as_uint(f);
    return (unsigned short)((u + 0x7fffu + ((u >> 16) & 1u)) >> 16);
}
__device__ __forceinline__ float bf2f(unsigned short s) {
    return __uint_as_float(((unsigned int)s) << 16);
}
__device__ __forceinline__ float sigm(float x) {
    return 1.0f / (1.0f + __expf(-x));
}
__device__ __forceinline__ float tanh_(float x) {
    float e = __expf(-2.0f * fabsf(x));       // (0,1], no overflow
    float r = (1.0f - e) / (1.0f + e);
    return copysignf(r, x);
}

// One block per 16 batch rows; 4 waves. Per step (MFMA, transposed form):
//   P[gate 256][batch 16] = Wcat[256][96] * [h_hi;h_lo;x]^T   (bf16 MFMA, fp32 acc)
// Wave w owns tiles (gate rows) {64G + 16w : G=0..3} = i/f/g/o for hid 16w..16w+15,
// so c/h update is lane-local & in-register across all steps. A-frags (weights)
// are constant in registers; per step each wave does 9 small LDS reads + 2 writes
// + 20 MFMAs + 1 barrier. h stored as bf16 hi+lo pair for precision.
__global__ __launch_bounds__(256, 1) void lstm_net_mfma(
    const float* __restrict__ x,     // [B, C, T]
    const float* __restrict__ W_ih,  // [4H, C]
    const float* __restrict__ W_hh,  // [4H, H]
    const float* __restrict__ b_ih,  // [4H]
    const float* __restrict__ b_hh,  // [4H]
    const float* __restrict__ W_fc,  // [NCLS, T*H]
    const float* __restrict__ b_fc,  // [NCLS]
    float* __restrict__ out)         // [B, NCLS]
{
    __shared__ uint4    xs[TC * 64];          // x chunk in B-frag layout, 51200 B
    __shared__ unsigned hhi[2][MB * HS];      // h_hi double buffer, bf16 pairs
    __shared__ unsigned hlo[2][MB * HS];      // h_lo double buffer
    __shared__ float    fcpart[4][MB][NCLS];  // FC partials per wave

    const int tid  = threadIdx.x;
    const int lane = tid & 63;
    const int w    = tid >> 6;     // wave id 0..3
    const int q    = lane >> 4;    // quad 0..3 (A/B frag k-block; C row-block)
    const int li   = lane & 15;    // A-frag row / B-frag col (batch)
    const int b0   = blockIdx.x * MB;

    // ---- constant A-fragments (weights) into registers ----
    s16x8 Ah0[4], Ah1[4], Ax[4];   // per gate-type tile G
    f32x4 bias[4];
    #pragma unroll
    for (int G = 0; G < 4; ++G) {
        const int row = G * 64 + w * 16 + li;          // gate row for A frag
        const float* wr = W_hh + row * HH;
        float4 w0 = *(const float4*)(wr + q * 8);
        float4 w1 = *(const float4*)(wr + q * 8 + 4);
        s16x8 a;
        a[0]=(short)f2bf(w0.x); a[1]=(short)f2bf(w0.y); a[2]=(short)f2bf(w0.z); a[3]=(short)f2bf(w0.w);
        a[4]=(short)f2bf(w1.x); a[5]=(short)f2bf(w1.y); a[6]=(short)f2bf(w1.z); a[7]=(short)f2bf(w1.w);
        Ah0[G] = a;
        float4 w2 = *(const float4*)(wr + 32 + q * 8);
        float4 w3 = *(const float4*)(wr + 32 + q * 8 + 4);
        a[0]=(short)f2bf(w2.x); a[1]=(short)f2bf(w2.y); a[2]=(short)f2bf(w2.z); a[3]=(short)f2bf(w2.w);
        a[4]=(short)f2bf(w3.x); a[5]=(short)f2bf(w3.y); a[6]=(short)f2bf(w3.z); a[7]=(short)f2bf(w3.w);
        Ah1[G] = a;
        s16x8 ax;
        #pragma unroll
        for (int j = 0; j < 8; ++j) {
            int c = q * 8 + j;
            float v = (c < CC) ? W_ih[row * CC + c] : 0.0f;
            ax[j] = (short)f2bf(v);
        }
        Ax[G] = ax;
        f32x4 bv;
        #pragma unroll
        for (int r = 0; r < 4; ++r) {
            int rb = G * 64 + w * 16 + q * 4 + r;      // C-layout row
            bv[r] = b_ih[rb] + b_hh[rb];
        }
        bias[G] = bv;
    }

    // lane owns (batch=li after MFMA? no: batch = li for frags; for C: batch=li)
    // C-tile: col(batch)=li, rows = 16w-group, hid = w*16 + q*4 + r
    const float* wfc0 = W_fc + 0 * (TT * HH) + (w * 16 + q * 4);
    const float* wfc1 = W_fc + 1 * (TT * HH) + (w * 16 + q * 4);
    const float* wfc2 = W_fc + 2 * (TT * HH) + (w * 16 + q * 4);
    const float* wfc3 = W_fc + 3 * (TT * HH) + (w * 16 + q * 4);

    float cr0 = 0.f, cr1 = 0.f, cr2 = 0.f, cr3 = 0.f;   // cell state (b=li, 4 hids)
    float fc0 = 0.f, fc1 = 0.f, fc2 = 0.f, fc3 = 0.f;   // FC partials (4 classes)

    // init LDS: zero xs (q=3 slots stay zero forever), zero h buffer p=0
    for (int i = tid; i < TC * 64; i += 256) xs[i] = (uint4){0u, 0u, 0u, 0u};
    {
        const int d = li * HS + 8 * w + 2 * q;   // this lane's h write slot
        hhi[0][d] = 0u; hhi[0][d + 1] = 0u;
        hlo[0][d] = 0u; hlo[0][d + 1] = 0u;
    }
    int p = 0;
    __syncthreads();

    for (int chunk = 0; chunk < NCHUNK; ++chunk) {
        // ---- stage x chunk into B-frag layout: xs[t][lane16B] ----
        for (int idx = tid; idx < TC * 48; idx += 256) {
            const int t  = idx / 48;
            const int rq = idx - t * 48;         // = r + 16*qq, qq<3
            const int r  = rq & 15;
            const int qq = rq >> 4;
            const float* gx = x + (b0 + r) * (CC * TT) + chunk * TC + t;
            unsigned short s[8];
            #pragma unroll
            for (int j = 0; j < 8; ++j) {
                int c = qq * 8 + j;
                float v = (c < CC) ? gx[c * TT] : 0.0f;
                s[j] = f2bf(v);
            }
            uint4 pk;
            pk.x = (unsigned)s[0] | ((unsigned)s[1] << 16);
            pk.y = (unsigned)s[2] | ((unsigned)s[3] << 16);
            pk.z = (unsigned)s[4] | ((unsigned)s[5] << 16);
            pk.w = (unsigned)s[6] | ((unsigned)s[7] << 16);
            xs[t * 64 + rq] = pk;
        }
        __syncthreads();

        for (int tt = 0; tt < TC; ++tt) {
            const int t = chunk * TC + tt;

            // ---- pre-barrier: x-part MFMA + W_fc prefetch (off critical path) ----
            U4 xu; xu.u = xs[tt * 64 + lane];
            f32x4 acc0 = __builtin_amdgcn_mfma_f32_16x16x32_bf16(Ax[0], xu.v, bias[0], 0, 0, 0);
            f32x4 acc1 = __builtin_amdgcn_mfma_f32_16x16x32_bf16(Ax[1], xu.v, bias[1], 0, 0, 0);
            f32x4 acc2 = __builtin_amdgcn_mfma_f32_16x16x32_bf16(Ax[2], xu.v, bias[2], 0, 0, 0);
            f32x4 acc3 = __builtin_amdgcn_mfma_f32_16x16x32_bf16(Ax[3], xu.v, bias[3], 0, 0, 0);
            float4 wv0 = *(const float4*)(wfc0 + t * HH);
            float4 wv1 = *(const float4*)(wfc1 + t * HH);
            float4 wv2 = *(const float4*)(wfc2 + t * HH);
            float4 wv3 = *(const float4*)(wfc3 + t * HH);

            __syncthreads();   // h[p] published by all waves

            // ---- B-frags: h_hi, h_lo (batch=li, hid k-block q) ----
            const unsigned* Hh = hhi[p];
            const unsigned* Hl = hlo[p];
            const int rb = li * HS;
            uint2 h00 = *(const uint2*)&Hh[rb + 4 * q];
            uint2 h01 = *(const uint2*)&Hh[rb + 4 * q + 2];
            uint2 h10 = *(const uint2*)&Hh[rb + 16 + 4 * q];
            uint2 h11 = *(const uint2*)&Hh[rb + 16 + 4 * q + 2];
            uint2 l00 = *(const uint2*)&Hl[rb + 4 * q];
            uint2 l01 = *(const uint2*)&Hl[rb + 4 * q + 2];
            uint2 l10 = *(const uint2*)&Hl[rb + 16 + 4 * q];
            uint2 l11 = *(const uint2*)&Hl[rb + 16 + 4 * q + 2];
            U4 Bhi0; Bhi0.u = (uint4){h00.x, h00.y, h01.x, h01.y};
            U4 Bhi1; Bhi1.u = (uint4){h10.x, h10.y, h11.x, h11.y};
            U4 Blo0; Blo0.u = (uint4){l00.x, l00.y, l01.x, l01.y};
            U4 Blo1; Blo1.u = (uint4){l10.x, l10.y, l11.x, l11.y};

            acc0 = __builtin_amdgcn_mfma_f32_16x16x32_bf16(Ah0[0], Bhi0.v, acc0, 0, 0, 0);
            acc1 = __builtin_amdgcn_mfma_f32_16x16x32_bf16(Ah0[1], Bhi0.v, acc1, 0, 0, 0);
            acc2 = __builtin_amdgcn_mfma_f32_16x16x32_bf16(Ah0[2], Bhi0.v, acc2, 0, 0, 0);
            acc3 = __builtin_amdgcn_mfma_f32_16x16x32_bf16(Ah0[3], Bhi0.v, acc3, 0, 0, 0);
            acc0 = __builtin_amdgcn_mfma_f32_16x16x32_bf16(Ah1[0], Bhi1.v, acc0, 0, 0, 0);
            acc1 = __builtin_amdgcn_mfma_f32_16x16x32_bf16(Ah1[1], Bhi1.v, acc1, 0, 0, 0);
            acc2 = __builtin_amdgcn_mfma_f32_16x16x32_bf16(Ah1[2], Bhi1.v, acc2, 0, 0, 0);
            acc3 = __builtin_amdgcn_mfma_f32_16x16x32_bf16(Ah1[3], Bhi1.v, acc3, 0, 0, 0);
            acc0 = __builtin_amdgcn_mfma_f32_16x16x32_bf16(Ah0[0], Blo0.v, acc0, 0, 0, 0);
            acc1 = __builtin_amdgcn_mfma_f32_16x16x32_bf16(Ah0[1], Blo0.v, acc1, 0, 0, 0);
            acc2 = __builtin_amdgcn_mfma_f32_16x16x32_bf16(Ah0[2], Blo0.v, acc2, 0, 0, 0);
            acc3 = __builtin_amdgcn_mfma_f32_16x16x32_bf16(Ah0[3], Blo0.v, acc3, 0, 0, 0);
            acc0 = __builtin_amdgcn_mfma_f32_16x16x32_bf16(Ah1[0], Blo1.v, acc0, 0, 0, 0);
            acc1 = __builtin_amdgcn_mfma_f32_16x16x32_bf16(Ah1[1], Blo1.v, acc1, 0, 0, 0);
            acc2 = __builtin_amdgcn_mfma_f32_16x16x32_bf16(Ah1[2], Blo1.v, acc2, 0, 0, 0);
            acc3 = __builtin_amdgcn_mfma_f32_16x16x32_bf16(Ah1[3], Blo1.v, acc3, 0, 0, 0);

            // ---- epilogue: activations, c/h update, FC, h split+publish ----
            unsigned hi01, hi23, lo01, lo23;
            {
                float iv, fv, gv, ov, h, hf;
                unsigned short hb, lb;

                iv = sigm(acc0[0]); fv = sigm(acc1[0]); gv = tanh_(acc2[0]); ov = sigm(acc3[0]);
                cr0 = fv * cr0 + iv * gv;  h = ov * tanh_(cr0);
                fc0 += h * wv0.x; fc1 += h * wv1.x; fc2 += h * wv2.x; fc3 += h * wv3.x;
                hb = f2bf(h); hf = bf2f(hb); lb = f2bf(h - hf);
                hi01 = (unsigned)hb; lo01 = (unsigned)lb;

                iv = sigm(acc0[1]); fv = sigm(acc1[1]); gv = tanh_(acc2[1]); ov = sigm(acc3[1]);
                cr1 = fv * cr1 + iv * gv;  h = ov * tanh_(cr1);
                fc0 += h * wv0.y; fc1 += h * wv1.y; fc2 += h * wv2.y; fc3 += h * wv3.y;
                hb = f2bf(h); hf = bf2f(hb); lb = f2bf(h - hf);
                hi01 |= ((unsigned)hb) << 16; lo01 |= ((unsigned)lb) << 16;

                iv = sigm(acc0[2]); fv = sigm(acc1[2]); gv = tanh_(acc2[2]); ov = sigm(acc3[2]);
                cr2 = fv * cr2 + iv * gv;  h = ov * tanh_(cr2);
                fc0 += h * wv0.z; fc1 += h * wv1.z; fc2 += h * wv2.z; fc3 += h * wv3.z;
                hb = f2bf(h); hf = bf2f(hb); lb = f2bf(h - hf);
                hi23 = (unsigned)hb; lo23 = (unsigned)lb;

                iv = sigm(acc0[3]); fv = sigm(acc1[3]); gv = tanh_(acc2[3]); ov = sigm(acc3[3]);
                cr3 = fv * cr3 + iv * gv;  h = ov * tanh_(cr3);
                fc0 += h * wv0.w; fc1 += h * wv1.w; fc2 += h * wv2.w; fc3 += h * wv3.w;
                hb = f2bf(h); hf = bf2f(hb); lb = f2bf(h - hf);
                hi23 |= ((unsigned)hb) << 16; lo23 |= ((unsigned)lb) << 16;
            }
            {
                unsigned* Wh = hhi[p ^ 1];
                unsigned* Wl = hlo[p ^ 1];
                const int d = li * HS + 8 * w + 2 * q;
                *(uint2*)&Wh[d] = (uint2){hi01, hi23};
                *(uint2*)&Wl[d] = (uint2){lo01, lo23};
            }
            p ^= 1;
        }
    }

    // ---- FC reduce: sum over hid (quads, then waves) ----
    fc0 += __shfl_down(fc0, 32); fc0 += __shfl_down(fc0, 16);
    fc1 += __shfl_down(fc1, 32); fc1 += __shfl_down(fc1, 16);
    fc2 += __shfl_down(fc2, 32); fc2 += __shfl_down(fc2, 16);
    fc3 += __shfl_down(fc3, 32); fc3 += __shfl_down(fc3, 16);
    if (lane < 16) {
        fcpart[w][lane][0] = fc0; fcpart[w][lane][1] = fc1;
        fcpart[w][lane][2] = fc2; fcpart[w][lane][3] = fc3;
    }
    __syncthreads();
    if (tid < MB * NCLS) {
        const int bb = tid >> 2, n = tid & 3;
        float lg = b_fc[n] + fcpart[0][bb][n] + fcpart[1][bb][n]
                 + fcpart[2][bb][n] + fcpart[3][bb][n];
        float mx = fmaxf(lg, __shfl_xor(lg, 1)); mx = fmaxf(mx, __shfl_xor(mx, 2));
        float e = __expf(lg - mx);
        float s = e + __shfl_xor(e, 1); s += __shfl_xor(s, 2);
        out[(b0 + bb) * NCLS + n] = e / s;
    }
}

extern "C" void kernel_launch(void* const* d_in, const int* in_sizes, int n_in,
                              void* d_out, int out_size, void* d_ws, size_t ws_size,
                              hipStream_t stream) {
    const float* x    = (const float*)d_in[0];
    const float* W_ih = (const float*)d_in[1];
    const float* W_hh = (const float*)d_in[2];
    const float* b_ih = (const float*)d_in[3];
    const float* b_hh = (const float*)d_in[4];
    const float* W_fc = (const float*)d_in[5];
    const float* b_fc = (const float*)d_in[6];
    float* out = (float*)d_out;

    lstm_net_mfma<<<NBLK, 256, 0, stream>>>(x, W_ih, W_hh, b_ih, b_hh, W_fc, b_fc, out);
}

// Round 3
// 683.593 us; speedup vs baseline: 1.9916x; 1.9916x over previous
//
#include <hip/hip_runtime.h>

// Problem constants
#define BB   512
#define CC   22
#define TT   1000
#define HH   64
#define NCLS 4
#define TC   250          // time chunk staged in LDS
#define NCHUNK (TT / TC)
#define XROW 12           // h2 slots per xs row (11 used, 48B rows, 16B aligned)

typedef _Float16 f16;
typedef __attribute__((ext_vector_type(2))) _Float16 h2;

__device__ __forceinline__ float sigm(float x) {
    return 1.0f / (1.0f + __expf(-x));
}
__device__ __forceinline__ float tanh_(float x) {
    float e = __expf(-2.0f * fabsf(x));   // (0,1], no overflow
    float r = (1.0f - e) / (1.0f + e);
    return copysignf(r, x);
}

// One wave per batch row; lane = hidden unit. Each lane computes ALL FOUR
// gates for its hid via v_dot2_f32_f16 (fp16 pairs, fp32 accumulate), so the
// c/h update is lane-local and the ONLY cross-lane dependency is the h
// broadcast through own-wave LDS (in-order DS ops, compiler lgkmcnt) —
// ZERO barriers in the whole kernel. W_fc is read from global per step; with
// no barrier the loads stay outstanding (vmcnt(N), no forced drain) and their
// latency hides under the 172-fdot2 dot phase.
__global__ __launch_bounds__(64, 1) void lstm_wave(
    const float* __restrict__ x,     // [B, C, T]
    const float* __restrict__ W_ih,  // [4H, C]
    const float* __restrict__ W_hh,  // [4H, H]
    const float* __restrict__ b_ih,  // [4H]
    const float* __restrict__ b_hh,  // [4H]
    const float* __restrict__ W_fc,  // [NCLS, T*H]
    const float* __restrict__ b_fc,  // [NCLS]
    float* __restrict__ out)         // [B, NCLS]
{
    __shared__ __align__(16) h2  xs[TC][XROW];   // 12 KB: x chunk, f16 pairs
    __shared__ __align__(16) f16 hbuf[HH];       // 128 B: h broadcast buffer

    const int lane = threadIdx.x;    // hidden unit
    const int r    = blockIdx.x;     // batch row

    // ---- per-lane weights into registers (one-time) ----
    h2 whh[4][32];      // W_hh rows for gates i,f,g,o of this hid (128 VGPR)
    h2 wih[4][11];      // W_ih rows (44 VGPR)
    float bias[4];
    #pragma unroll
    for (int g = 0; g < 4; ++g) {
        const int row = g * HH + lane;
        const float* wr = W_hh + row * HH;
        #pragma unroll
        for (int k = 0; k < 32; ++k)
            whh[g][k] = h2{(f16)wr[2 * k], (f16)wr[2 * k + 1]};
        const float* wi = W_ih + row * CC;
        #pragma unroll
        for (int k = 0; k < 11; ++k)
            wih[g][k] = h2{(f16)wi[2 * k], (f16)wi[2 * k + 1]};
        bias[g] = b_ih[row] + b_hh[row];
    }

    hbuf[lane] = (f16)0.0f;          // in-wave ordering; no barrier needed
    float c = 0.0f;
    float fc0 = 0.f, fc1 = 0.f, fc2 = 0.f, fc3 = 0.f;
    const float* p0 = W_fc + 0 * (TT * HH) + lane;
    const float* p1 = W_fc + 1 * (TT * HH) + lane;
    const float* p2 = W_fc + 2 * (TT * HH) + lane;
    const float* p3 = W_fc + 3 * (TT * HH) + lane;
    const float* xrow = x + (size_t)r * (CC * TT);

    for (int chunk = 0; chunk < NCHUNK; ++chunk) {
        // ---- stage own row's x chunk into LDS as f16 pairs (off-chain) ----
        for (int tb = 0; tb < TC; tb += 64) {
            const int t = tb + lane;
            if (t < TC) {
                const float* gx = xrow + chunk * TC + t;   // stride TT between channels
                union { h2 h[XROW]; uint4 q[3]; } U;
                #pragma unroll
                for (int k = 0; k < 11; ++k)
                    U.h[k] = h2{(f16)gx[(2 * k) * TT], (f16)gx[(2 * k + 1) * TT]};
                U.h[11] = h2{(f16)0.0f, (f16)0.0f};
                uint4* dst = (uint4*)&xs[t][0];
                dst[0] = U.q[0]; dst[1] = U.q[1]; dst[2] = U.q[2];
            }
        }
        // no __syncthreads: xs is own-wave data, DS ops are in-order per wave

        for (int tt = 0; tt < TC; ++tt) {
            // h broadcast (8 x ds_read_b128, all lanes same address)
            union { uint4 q[8]; h2 h[32]; } H;
            const uint4* hr = (const uint4*)hbuf;
            #pragma unroll
            for (int i = 0; i < 8; ++i) H.q[i] = hr[i];

            // x broadcast (3 x ds_read_b128)
            union { uint4 q[3]; h2 h[XROW]; } X;
            const uint4* xr = (const uint4*)&xs[tt][0];
            X.q[0] = xr[0]; X.q[1] = xr[1]; X.q[2] = xr[2];

            // W_fc for this step (global, no barrier -> latency hidden)
            float w0 = *p0, w1 = *p1, w2 = *p2, w3 = *p3;
            p0 += HH; p1 += HH; p2 += HH; p3 += HH;

            // 4 gate dots: x part first (independent of h read), then h part
            float a0 = bias[0], a1 = bias[1], a2 = bias[2], a3 = bias[3];
            #pragma unroll
            for (int k = 0; k < 11; ++k) {
                a0 = __builtin_amdgcn_fdot2(X.h[k], wih[0][k], a0, false);
                a1 = __builtin_amdgcn_fdot2(X.h[k], wih[1][k], a1, false);
                a2 = __builtin_amdgcn_fdot2(X.h[k], wih[2][k], a2, false);
                a3 = __builtin_amdgcn_fdot2(X.h[k], wih[3][k], a3, false);
            }
            #pragma unroll
            for (int k = 0; k < 32; ++k) {
                a0 = __builtin_amdgcn_fdot2(H.h[k], whh[0][k], a0, false);
                a1 = __builtin_amdgcn_fdot2(H.h[k], whh[1][k], a1, false);
                a2 = __builtin_amdgcn_fdot2(H.h[k], whh[2][k], a2, false);
                a3 = __builtin_amdgcn_fdot2(H.h[k], whh[3][k], a3, false);
            }

            // lane-local LSTM update
            float iv = sigm(a0), fv = sigm(a1), gv = tanh_(a2), ov = sigm(a3);
            c = fv * c + iv * gv;
            float h = ov * tanh_(c);

            // fused FC accumulation (fp32 h, fp32 W_fc)
            fc0 += h * w0; fc1 += h * w1; fc2 += h * w2; fc3 += h * w3;

            // publish h for next step (in-wave LDS, single buffer is safe:
            // this step's reads completed before this write issues)
            hbuf[lane] = (f16)h;
        }
    }

    // ---- FC reduce over hid (wave shuffle) + softmax ----
    #pragma unroll
    for (int off = 32; off; off >>= 1) {
        fc0 += __shfl_down(fc0, off);
        fc1 += __shfl_down(fc1, off);
        fc2 += __shfl_down(fc2, off);
        fc3 += __shfl_down(fc3, off);
    }
    if (lane == 0) {
        float l0 = fc0 + b_fc[0], l1 = fc1 + b_fc[1];
        float l2 = fc2 + b_fc[2], l3 = fc3 + b_fc[3];
        float m  = fmaxf(fmaxf(l0, l1), fmaxf(l2, l3));
        float e0 = __expf(l0 - m), e1 = __expf(l1 - m);
        float e2 = __expf(l2 - m), e3 = __expf(l3 - m);
        float s  = e0 + e1 + e2 + e3;
        float4 o; o.x = e0 / s; o.y = e1 / s; o.z = e2 / s; o.w = e3 / s;
        *(float4*)(out + r * NCLS) = o;
    }
}

extern "C" void kernel_launch(void* const* d_in, const int* in_sizes, int n_in,
                              void* d_out, int out_size, void* d_ws, size_t ws_size,
                              hipStream_t stream) {
    const float* x    = (const float*)d_in[0];
    const float* W_ih = (const float*)d_in[1];
    const float* W_hh = (const float*)d_in[2];
    const float* b_ih = (const float*)d_in[3];
    const float* b_hh = (const float*)d_in[4];
    const float* W_fc = (const float*)d_in[5];
    const float* b_fc = (const float*)d_in[6];
    float* out = (float*)d_out;

    lstm_wave<<<BB, 64, 0, stream>>>(x, W_ih, W_hh, b_ih, b_hh, W_fc, b_fc, out);
}

// Round 4
// 681.216 us; speedup vs baseline: 1.9985x; 1.0035x over previous
//
#include <hip/hip_runtime.h>

// Problem constants
#define BB   512
#define CC   22
#define TT   1000
#define HH   64
#define NCLS 4
#define TC   250          // time chunk staged in LDS
#define NCHUNK (TT / TC)
#define XROW 12           // h2 slots per xs row (11 used, 48B rows, 16B aligned)

typedef _Float16 f16;
typedef __attribute__((ext_vector_type(2))) _Float16 h2;

__device__ __forceinline__ float sigm(float x) {
    return 1.0f / (1.0f + __expf(-x));
}
__device__ __forceinline__ float tanh_(float x) {
    float e = __expf(-2.0f * fabsf(x));   // (0,1], no overflow
    float r = (1.0f - e) / (1.0f + e);
    return copysignf(r, x);
}

__device__ __forceinline__ h2 u2h(unsigned u) {
    union { unsigned u; h2 h; } c; c.u = u; return c.h;
}
__device__ __forceinline__ unsigned h2u(h2 h) {
    union { unsigned u; h2 h; } c; c.h = h; return c.u;
}

// One wave per batch row; lane = hidden unit; each lane computes all 4 gates
// for its hid via v_dot2_f32_f16. Zero barriers: the only cross-lane dep is
// the h broadcast through own-wave LDS (in-order DS pipe).
// R4 fix: weights are PINNED into VGPRs via empty asm("+v") after the one-time
// load — R3's VGPR_Count=132 < the 172-reg weight footprint proved the
// compiler was rematerializing the weight loads (or spilling) inside the
// 1000-step loop, costing ~1000 stall cyc/step.
__global__ __launch_bounds__(64, 1) void lstm_wave(
    const float* __restrict__ x,     // [B, C, T]
    const float* __restrict__ W_ih,  // [4H, C]
    const float* __restrict__ W_hh,  // [4H, H]
    const float* __restrict__ b_ih,  // [4H]
    const float* __restrict__ b_hh,  // [4H]
    const float* __restrict__ W_fc,  // [NCLS, T*H]
    const float* __restrict__ b_fc,  // [NCLS]
    float* __restrict__ out)         // [B, NCLS]
{
    __shared__ __align__(16) h2  xs[TC][XROW];   // 12 KB: x chunk, f16 pairs
    __shared__ __align__(16) f16 hbuf[HH];       // 128 B: h broadcast buffer

    const int lane = threadIdx.x;    // hidden unit
    const int r    = blockIdx.x;     // batch row

    // ---- per-lane weights into registers (one-time), then PIN them ----
    unsigned whh[4][32];      // W_hh rows (f16 pairs) for gates i,f,g,o: 128 VGPR
    unsigned wih[4][11];      // W_ih rows: 44 VGPR
    float bias[4];
    #pragma unroll
    for (int g = 0; g < 4; ++g) {
        const int row = g * HH + lane;
        const float* wr = W_hh + row * HH;
        #pragma unroll
        for (int k = 0; k < 32; ++k)
            whh[g][k] = h2u(h2{(f16)wr[2 * k], (f16)wr[2 * k + 1]});
        const float* wi = W_ih + row * CC;
        #pragma unroll
        for (int k = 0; k < 11; ++k)
            wih[g][k] = h2u(h2{(f16)wi[2 * k], (f16)wi[2 * k + 1]});
        bias[g] = b_ih[row] + b_hh[row];
    }
    #pragma unroll
    for (int g = 0; g < 4; ++g) {
        #pragma unroll
        for (int k = 0; k < 32; ++k) asm volatile("" : "+v"(whh[g][k]));
        #pragma unroll
        for (int k = 0; k < 11; ++k) asm volatile("" : "+v"(wih[g][k]));
        asm volatile("" : "+v"(bias[g]));
    }

    hbuf[lane] = (f16)0.0f;          // in-wave ordering; no barrier needed
    float c = 0.0f;
    float fc0 = 0.f, fc1 = 0.f, fc2 = 0.f, fc3 = 0.f;
    const float* p0 = W_fc + 0 * (TT * HH) + lane;
    const float* p1 = W_fc + 1 * (TT * HH) + lane;
    const float* p2 = W_fc + 2 * (TT * HH) + lane;
    const float* p3 = W_fc + 3 * (TT * HH) + lane;
    const float* xrow = x + (size_t)r * (CC * TT);

    for (int chunk = 0; chunk < NCHUNK; ++chunk) {
        // ---- stage own row's x chunk into LDS as f16 pairs (off-chain) ----
        for (int tb = 0; tb < TC; tb += 64) {
            const int t = tb + lane;
            if (t < TC) {
                const float* gx = xrow + chunk * TC + t;   // stride TT between channels
                union { h2 h[XROW]; uint4 q[3]; } U;
                #pragma unroll
                for (int k = 0; k < 11; ++k)
                    U.h[k] = h2{(f16)gx[(2 * k) * TT], (f16)gx[(2 * k + 1) * TT]};
                U.h[11] = h2{(f16)0.0f, (f16)0.0f};
                uint4* dst = (uint4*)&xs[t][0];
                dst[0] = U.q[0]; dst[1] = U.q[1]; dst[2] = U.q[2];
            }
        }
        // no __syncthreads: xs is own-wave data, DS ops are in-order per wave

        for (int tt = 0; tt < TC; ++tt) {
            // h broadcast (8 x ds_read_b128, all lanes same address)
            union { uint4 q[8]; h2 h[32]; } H;
            const uint4* hr = (const uint4*)hbuf;
            #pragma unroll
            for (int i = 0; i < 8; ++i) H.q[i] = hr[i];

            // x broadcast (3 x ds_read_b128)
            union { uint4 q[3]; h2 h[XROW]; } X;
            const uint4* xr = (const uint4*)&xs[tt][0];
            X.q[0] = xr[0]; X.q[1] = xr[1]; X.q[2] = xr[2];

            // W_fc for this step (global, no barrier -> latency hidden)
            float w0 = *p0, w1 = *p1, w2 = *p2, w3 = *p3;
            p0 += HH; p1 += HH; p2 += HH; p3 += HH;

            // 4 gate dots: x part first (independent of h read), then h part
            float a0 = bias[0], a1 = bias[1], a2 = bias[2], a3 = bias[3];
            #pragma unroll
            for (int k = 0; k < 11; ++k) {
                a0 = __builtin_amdgcn_fdot2(X.h[k], u2h(wih[0][k]), a0, false);
                a1 = __builtin_amdgcn_fdot2(X.h[k], u2h(wih[1][k]), a1, false);
                a2 = __builtin_amdgcn_fdot2(X.h[k], u2h(wih[2][k]), a2, false);
                a3 = __builtin_amdgcn_fdot2(X.h[k], u2h(wih[3][k]), a3, false);
            }
            #pragma unroll
            for (int k = 0; k < 32; ++k) {
                a0 = __builtin_amdgcn_fdot2(H.h[k], u2h(whh[0][k]), a0, false);
                a1 = __builtin_amdgcn_fdot2(H.h[k], u2h(whh[1][k]), a1, false);
                a2 = __builtin_amdgcn_fdot2(H.h[k], u2h(whh[2][k]), a2, false);
                a3 = __builtin_amdgcn_fdot2(H.h[k], u2h(whh[3][k]), a3, false);
            }

            // lane-local LSTM update
            float iv = sigm(a0), fv = sigm(a1), gv = tanh_(a2), ov = sigm(a3);
            c = fv * c + iv * gv;
            float h = ov * tanh_(c);

            // fused FC accumulation (fp32 h, fp32 W_fc)
            fc0 += h * w0; fc1 += h * w1; fc2 += h * w2; fc3 += h * w3;

            // publish h for next step (in-wave LDS, single buffer is safe:
            // this step's reads completed before this write issues)
            hbuf[lane] = (f16)h;
        }
    }

    // ---- FC reduce over hid (wave shuffle) + softmax ----
    #pragma unroll
    for (int off = 32; off; off >>= 1) {
        fc0 += __shfl_down(fc0, off);
        fc1 += __shfl_down(fc1, off);
        fc2 += __shfl_down(fc2, off);
        fc3 += __shfl_down(fc3, off);
    }
    if (lane == 0) {
        float l0 = fc0 + b_fc[0], l1 = fc1 + b_fc[1];
        float l2 = fc2 + b_fc[2], l3 = fc3 + b_fc[3];
        float m  = fmaxf(fmaxf(l0, l1), fmaxf(l2, l3));
        float e0 = __expf(l0 - m), e1 = __expf(l1 - m);
        float e2 = __expf(l2 - m), e3 = __expf(l3 - m);
        float s  = e0 + e1 + e2 + e3;
        float4 o; o.x = e0 / s; o.y = e1 / s; o.z = e2 / s; o.w = e3 / s;
        *(float4*)(out + r * NCLS) = o;
    }
}

extern "C" void kernel_launch(void* const* d_in, const int* in_sizes, int n_in,
                              void* d_out, int out_size, void* d_ws, size_t ws_size,
                              hipStream_t stream) {
    const float* x    = (const float*)d_in[0];
    const float* W_ih = (const float*)d_in[1];
    const float* W_hh = (const float*)d_in[2];
    const float* b_ih = (const float*)d_in[3];
    const float* b_hh = (const float*)d_in[4];
    const float* W_fc = (const float*)d_in[5];
    const float* b_fc = (const float*)d_in[6];
    float* out = (float*)d_out;

    lstm_wave<<<BB, 64, 0, stream>>>(x, W_ih, W_hh, b_ih, b_hh, W_fc, b_fc, out);
}